// Round 5
// baseline (245.662 us; speedup 1.0000x reference)
//
#include <hip/hip_runtime.h>
#include <hip/hip_bf16.h>

// GAT-style graph attention. N=50000, E=600000, FEAT=128, H=8, D=16.
// R14: R13 was NULL (48.2->48.0) — vmem count dropped 6x but the 48-shfl+
//      48-add full butterfly per node replaced it instruction-for-instruction
//      (VALUBusy 27->37%, LDS-conflict 200K->300K). This round cuts BOTH
//      instruction count and stall:
//      (a) reduce-scatter replaces butterfly: keep/give + shfl_xor(8/16/32)
//          on 8->4->2 dims = 14 shfl + ~42 VALU (vs 48+96); final all-64-lane
//          parallel 4B LDS write (no j==0 divergence).
//      (b) gather + sumexp edge loops unrolled x2 (16 edges, 2x loads in
//          flight; P(deg<=16)~90% -> single trip).
//      (c) rec stores s<<8 (byte row-offset): kills a v_mul per Q/V address
//          chain in both edge kernels (segsum idx = rec>>5).
//      Everything else unchanged from R13.

#define FEAT 128
#define NHEAD 8
#define NPAD 50048   // N rounded up to multiple of 64

typedef __attribute__((ext_vector_type(8))) short bf16x8;
typedef __attribute__((ext_vector_type(4))) float f32x4;

__device__ __forceinline__ unsigned short f2bf(float f) {
    unsigned u = __float_as_uint(f);
    u += 0x7fffu + ((u >> 16) & 1u);
    return (unsigned short)(u >> 16);
}
__device__ __forceinline__ float bf2f_lo(unsigned u) { return __uint_as_float(u << 16); }
__device__ __forceinline__ float bf2f_hi(unsigned u) { return __uint_as_float(u & 0xffff0000u); }
__device__ __forceinline__ float bfw(unsigned short u) { return __uint_as_float((unsigned)u << 16); }

// ---- fused prep: dest histogram (+rank capture) | convert_x | convert_w ----
__global__ __launch_bounds__(256) void prep_kernel(
    const int* __restrict__ dsts, int* __restrict__ counts, int* __restrict__ rank,
    const float* __restrict__ X, unsigned short* __restrict__ Xb, int total8,
    const float* __restrict__ Wq, const float* __restrict__ Wk,
    const float* __restrict__ Wv, const float* __restrict__ Wo,
    unsigned short* __restrict__ Wb,
    int E, int histBlocks, int convxBlocks)
{
    int b = blockIdx.x;
    if (b < histBlocks) {
        int e = b * 256 + threadIdx.x;
        if (e < E) rank[e] = atomicAdd(counts + dsts[e], 1);
        return;
    }
    b -= histBlocks;
    if (b < convxBlocks) {
        int i = b * 256 + threadIdx.x;
        if (i >= total8) return;
        const float4* xp = (const float4*)X + (size_t)i * 2;
        float4 x0 = xp[0], x1 = xp[1];
        uint4 o;
        o.x = (unsigned)f2bf(x0.x) | ((unsigned)f2bf(x0.y) << 16);
        o.y = (unsigned)f2bf(x0.z) | ((unsigned)f2bf(x0.w) << 16);
        o.z = (unsigned)f2bf(x1.x) | ((unsigned)f2bf(x1.y) << 16);
        o.w = (unsigned)f2bf(x1.z) | ((unsigned)f2bf(x1.w) << 16);
        ((uint4*)Xb)[i] = o;
        return;
    }
    b -= convxBlocks;
    int i = b * 256 + threadIdx.x;
    if (i >= 4 * 2048) return;
    int mat = i >> 11, idx = i & 2047;
    const float* W = (mat == 0) ? Wq : (mat == 1) ? Wk : (mat == 2) ? Wv : Wo;
    const float4* xp = (const float4*)W + (size_t)idx * 2;
    float4 x0 = xp[0], x1 = xp[1];
    uint4 o;
    o.x = (unsigned)f2bf(x0.x) | ((unsigned)f2bf(x0.y) << 16);
    o.y = (unsigned)f2bf(x0.z) | ((unsigned)f2bf(x0.w) << 16);
    o.z = (unsigned)f2bf(x1.x) | ((unsigned)f2bf(x1.y) << 16);
    o.w = (unsigned)f2bf(x1.z) | ((unsigned)f2bf(x1.w) << 16);
    ((uint4*)(Wb + (size_t)mat * 16384))[idx] = o;
}

// ---- scan: per-256-block exclusive scan of counts; last block scans the
//      block sums. Also zeroes segsum. Consumers add blockoffs[i>>8]. ----
__global__ __launch_bounds__(256) void scan12_kernel(
    const int* __restrict__ counts, int* __restrict__ offsets,
    int* __restrict__ blocksums, int* __restrict__ blockoffs,
    int* __restrict__ done, float4* __restrict__ segsum4,
    int NT, int NB, int NSEG)
{
    __shared__ int buf[256];
    __shared__ int amLast;
    int t = threadIdx.x, b = blockIdx.x;
    int i = b * 256 + t;
    if (i < NSEG) {   // zero segsum: 8 f32 per thread
        float4 z = {0.f, 0.f, 0.f, 0.f};
        segsum4[(size_t)i * 2] = z;
        segsum4[(size_t)i * 2 + 1] = z;
    }
    int v = (i < NT) ? counts[i] : 0;
    buf[t] = v; __syncthreads();
    int x = v;
    #pragma unroll
    for (int off = 1; off < 256; off <<= 1) {
        int y = (t >= off) ? buf[t - off] : 0;
        __syncthreads();
        x += y; buf[t] = x;
        __syncthreads();
    }
    if (i < NT) offsets[i] = x - v;
    if (t == 255) {
        blocksums[b] = x;
        __threadfence();
        amLast = (atomicAdd(done, 1) == (int)gridDim.x - 1);
    }
    __syncthreads();
    if (!amLast) return;
    int v2 = (t < NB)
        ? __hip_atomic_load(&blocksums[t], __ATOMIC_ACQUIRE, __HIP_MEMORY_SCOPE_AGENT)
        : 0;
    buf[t] = v2; __syncthreads();
    int x2 = v2;
    #pragma unroll
    for (int off = 1; off < 256; off <<= 1) {
        int y = (t >= off) ? buf[t - off] : 0;
        __syncthreads();
        x2 += y; buf[t] = x2;
        __syncthreads();
    }
    if (t < NB) blockoffs[t] = x2 - v2;
}

// ---- combined: QKV MFMA GEMM + dest-CSR fill (hidden under the GEMM).
//      rec stores s<<8 = byte offset of row s in the 256B-row arrays. ----
__global__ __launch_bounds__(256) void fillqkv_kernel(
    const unsigned short* __restrict__ Xb, const unsigned short* __restrict__ Wb,
    const float* __restrict__ bq, const float* __restrict__ bk, const float* __restrict__ bv,
    unsigned short* __restrict__ Q, unsigned short* __restrict__ K,
    unsigned short* __restrict__ V, int N, int numTiles, int qkvBlocks,
    const int* __restrict__ srcs, const int* __restrict__ dsts,
    const int* __restrict__ rank, const int* __restrict__ offsets,
    const int* __restrict__ blockoffs, int* __restrict__ rec, int E)
{
    if (blockIdx.x >= qkvBlocks) {
        int e = (blockIdx.x - qkvBlocks) * 256 + threadIdx.x;
        if (e < E) {
            int s = srcs[e], d = dsts[e];
            rec[offsets[d] + blockoffs[d >> 8] + rank[e]] = s << 8;
        }
        return;
    }

    const int lane = threadIdx.x & 63;
    const int wave = threadIdx.x >> 6;
    const int m = lane & 15, quad = lane >> 4;
    const int colbase = wave * 32;

    bf16x8 bfr[3][2][4];
    #pragma unroll
    for (int mat = 0; mat < 3; mat++)
        #pragma unroll
        for (int ctl = 0; ctl < 2; ctl++) {
            const unsigned short* wrow =
                Wb + mat * 16384 + (size_t)(colbase + ctl * 16 + m) * FEAT + quad * 8;
            #pragma unroll
            for (int kc = 0; kc < 4; kc++)
                bfr[mat][ctl][kc] = *(const bf16x8*)(wrow + kc * 32);
        }

    const float* bias_p[3] = {bq, bk, bv};
    float bias[3][2];
    #pragma unroll
    for (int mat = 0; mat < 3; mat++)
        #pragma unroll
        for (int ctl = 0; ctl < 2; ctl++)
            bias[mat][ctl] = bias_p[mat][colbase + ctl * 16 + m];

    unsigned short* outp[3] = {Q, K, V};

    for (int tile = blockIdx.x; tile < numTiles; tile += qkvBlocks) {
        const int row0 = tile * 16;
        const unsigned short* arow = Xb + (size_t)(row0 + m) * FEAT + quad * 8;
        bf16x8 a[4];
        #pragma unroll
        for (int kc = 0; kc < 4; kc++) a[kc] = *(const bf16x8*)(arow + kc * 32);
        f32x4 acc[3][2];
        #pragma unroll
        for (int mat = 0; mat < 3; mat++)
            #pragma unroll
            for (int ctl = 0; ctl < 2; ctl++) acc[mat][ctl] = (f32x4){0.f, 0.f, 0.f, 0.f};
        #pragma unroll
        for (int kc = 0; kc < 4; kc++)
            #pragma unroll
            for (int mat = 0; mat < 3; mat++)
                #pragma unroll
                for (int ctl = 0; ctl < 2; ctl++)
                    acc[mat][ctl] = __builtin_amdgcn_mfma_f32_16x16x32_bf16(
                        a[kc], bfr[mat][ctl][kc], acc[mat][ctl], 0, 0, 0);
        #pragma unroll
        for (int mat = 0; mat < 3; mat++)
            #pragma unroll
            for (int ctl = 0; ctl < 2; ctl++)
                #pragma unroll
                for (int reg = 0; reg < 4; reg++) {
                    int row = row0 + quad * 4 + reg;
                    if (row < N)
                        outp[mat][(size_t)row * FEAT + colbase + ctl * 16 + m] =
                            f2bf(acc[mat][ctl][reg] + bias[mat][ctl]);
                }
    }
}

// ---- sumexp: one wave per DEST node, shfl-free, unrolled x2.
//      rec holds byte row-offsets (s<<8); segsum idx = rec>>5 (+h). ----
__global__ __launch_bounds__(256) void sumexp_kernel(
    const int* __restrict__ offsets, const int* __restrict__ blockoffs,
    const int* __restrict__ counts, const int* __restrict__ rec,
    const unsigned short* __restrict__ Q, const unsigned short* __restrict__ K,
    unsigned short* __restrict__ wrawb, float* __restrict__ segsum, int N)
{
    int node = blockIdx.x * 4 + (threadIdx.x >> 6);
    if (node >= N) return;
    int lane = threadIdx.x & 63;
    int j = lane >> 3, h = lane & 7;
    int start = offsets[node] + blockoffs[node >> 8];
    int deg = counts[node];
    if (deg == 0) return;

    float kf[16];
    {
        const unsigned* kp = (const unsigned*)(K + (size_t)node * FEAT + h * 16);
        #pragma unroll
        for (int i = 0; i < 8; i++) {
            unsigned u = kp[i];
            kf[2 * i]     = bf2f_lo(u);
            kf[2 * i + 1] = bf2f_hi(u);
        }
    }

    for (int j0 = 0; j0 < deg; j0 += 16) {
        int jjA = j0 + j, jjB = j0 + 8 + j;
        bool actA = jjA < deg, actB = jjB < deg;
        int posA = start + (actA ? jjA : 0);
        int posB = start + (actB ? jjB : 0);
        int rA = rec[posA], rB = rec[posB];
        const unsigned* qpA = (const unsigned*)((const char*)Q + (size_t)rA + h * 32);
        const unsigned* qpB = (const unsigned*)((const char*)Q + (size_t)rB + h * 32);
        uint4 qaA = *(const uint4*)qpA;
        uint4 qbA = *(const uint4*)(qpA + 4);
        uint4 qaB = *(const uint4*)qpB;
        uint4 qbB = *(const uint4*)(qpB + 4);
        float pA, pB;
        pA  = bf2f_lo(qaA.x) * kf[0]  + bf2f_hi(qaA.x) * kf[1];
        pA += bf2f_lo(qaA.y) * kf[2]  + bf2f_hi(qaA.y) * kf[3];
        pA += bf2f_lo(qaA.z) * kf[4]  + bf2f_hi(qaA.z) * kf[5];
        pA += bf2f_lo(qaA.w) * kf[6]  + bf2f_hi(qaA.w) * kf[7];
        pA += bf2f_lo(qbA.x) * kf[8]  + bf2f_hi(qbA.x) * kf[9];
        pA += bf2f_lo(qbA.y) * kf[10] + bf2f_hi(qbA.y) * kf[11];
        pA += bf2f_lo(qbA.z) * kf[12] + bf2f_hi(qbA.z) * kf[13];
        pA += bf2f_lo(qbA.w) * kf[14] + bf2f_hi(qbA.w) * kf[15];
        pB  = bf2f_lo(qaB.x) * kf[0]  + bf2f_hi(qaB.x) * kf[1];
        pB += bf2f_lo(qaB.y) * kf[2]  + bf2f_hi(qaB.y) * kf[3];
        pB += bf2f_lo(qaB.z) * kf[4]  + bf2f_hi(qaB.z) * kf[5];
        pB += bf2f_lo(qaB.w) * kf[6]  + bf2f_hi(qaB.w) * kf[7];
        pB += bf2f_lo(qbB.x) * kf[8]  + bf2f_hi(qbB.x) * kf[9];
        pB += bf2f_lo(qbB.y) * kf[10] + bf2f_hi(qbB.y) * kf[11];
        pB += bf2f_lo(qbB.z) * kf[12] + bf2f_hi(qbB.z) * kf[13];
        pB += bf2f_lo(qbB.w) * kf[14] + bf2f_hi(qbB.w) * kf[15];
        float wA = __expf(pA * 0.25f);
        float wB = __expf(pB * 0.25f);
        if (actA) {
            wrawb[(size_t)posA * NHEAD + h] = f2bf(wA);
            atomicAdd(segsum + (rA >> 5) + h, wA);
        }
        if (actB) {
            wrawb[(size_t)posB * NHEAD + h] = f2bf(wB);
            atomicAdd(segsum + (rB >> 5) + h, wB);
        }
    }
}

// ---- scale V in place by 1/segsum per (node, head) ----
__global__ __launch_bounds__(256) void scalev_kernel(
    const float* __restrict__ segsum, unsigned short* __restrict__ V, int total16)
{
    int i = blockIdx.x * 256 + threadIdx.x;
    if (i >= total16) return;
    int s = i >> 4;
    int part = i & 15;
    int h = part >> 1;
    float r = 1.0f / segsum[s * NHEAD + h];
    uint4* p = (uint4*)(V + (size_t)s * FEAT) + part;
    uint4 v = *p;
    uint4 o;
    o.x = (unsigned)f2bf(bf2f_lo(v.x) * r) | ((unsigned)f2bf(bf2f_hi(v.x) * r) << 16);
    o.y = (unsigned)f2bf(bf2f_lo(v.y) * r) | ((unsigned)f2bf(bf2f_hi(v.y) * r) << 16);
    o.z = (unsigned)f2bf(bf2f_lo(v.z) * r) | ((unsigned)f2bf(bf2f_hi(v.z) * r) << 16);
    o.w = (unsigned)f2bf(bf2f_lo(v.w) * r) | ((unsigned)f2bf(bf2f_hi(v.w) * r) << 16);
    *p = o;
}

// ---- fused gather + out GEMM: block owns 16 dest nodes.
//      Phase 1: lane=(edge-slot j, head h); unrolled x2 (16 edges in
//      flight). Reduce-scatter over j-bits: keep/give + shfl_xor(8/16/32)
//      on 8->4->2 dims; every lane ends owning a consecutive dim-pair ->
//      fully parallel 64-lane LDS write. Phase 2: 16x128 MFMA @ Wo^T. ----
__global__ __launch_bounds__(256) void gatherout_kernel(
    const int* __restrict__ offsets, const int* __restrict__ blockoffs,
    const int* __restrict__ counts, const int* __restrict__ rec,
    const unsigned short* __restrict__ wrawb, const unsigned short* __restrict__ V,
    const unsigned short* __restrict__ Wob, const float* __restrict__ bo,
    float* __restrict__ out, int N)
{
    __shared__ unsigned short lds[16][136];
    const int wave = threadIdx.x >> 6;
    const int lane = threadIdx.x & 63;
    const int j = lane >> 3, h = lane & 7;
    const int b0 = j & 1, b1 = (j >> 1) & 1, b2 = (j >> 2) & 1;
    const int dbase = b0 * 8 + b1 * 4 + b2 * 2;

    for (int i = 0; i < 4; i++) {
        int node = blockIdx.x * 16 + wave * 4 + i;
        float acc[16];
        #pragma unroll
        for (int d = 0; d < 16; d++) acc[d] = 0.f;
        if (node < N) {
            int start = offsets[node] + blockoffs[node >> 8];
            int deg = counts[node];
            for (int j0 = 0; j0 < deg; j0 += 16) {
                int jjA = j0 + j, jjB = j0 + 8 + j;
                bool actA = jjA < deg, actB = jjB < deg;
                int posA = start + (actA ? jjA : 0);
                int posB = start + (actB ? jjB : 0);
                int rA = rec[posA], rB = rec[posB];
                float wA = actA ? bfw(wrawb[(size_t)posA * NHEAD + h]) : 0.f;
                float wB = actB ? bfw(wrawb[(size_t)posB * NHEAD + h]) : 0.f;
                const uint4* vpA = (const uint4*)((const char*)V + (size_t)rA + h * 32);
                const uint4* vpB = (const uint4*)((const char*)V + (size_t)rB + h * 32);
                uint4 vaA = vpA[0], vbA = vpA[1];
                uint4 vaB = vpB[0], vbB = vpB[1];
                acc[0]  += wA * bf2f_lo(vaA.x); acc[1]  += wA * bf2f_hi(vaA.x);
                acc[2]  += wA * bf2f_lo(vaA.y); acc[3]  += wA * bf2f_hi(vaA.y);
                acc[4]  += wA * bf2f_lo(vaA.z); acc[5]  += wA * bf2f_hi(vaA.z);
                acc[6]  += wA * bf2f_lo(vaA.w); acc[7]  += wA * bf2f_hi(vaA.w);
                acc[8]  += wA * bf2f_lo(vbA.x); acc[9]  += wA * bf2f_hi(vbA.x);
                acc[10] += wA * bf2f_lo(vbA.y); acc[11] += wA * bf2f_hi(vbA.y);
                acc[12] += wA * bf2f_lo(vbA.z); acc[13] += wA * bf2f_hi(vbA.z);
                acc[14] += wA * bf2f_lo(vbA.w); acc[15] += wA * bf2f_hi(vbA.w);
                acc[0]  += wB * bf2f_lo(vaB.x); acc[1]  += wB * bf2f_hi(vaB.x);
                acc[2]  += wB * bf2f_lo(vaB.y); acc[3]  += wB * bf2f_hi(vaB.y);
                acc[4]  += wB * bf2f_lo(vaB.z); acc[5]  += wB * bf2f_hi(vaB.z);
                acc[6]  += wB * bf2f_lo(vaB.w); acc[7]  += wB * bf2f_hi(vaB.w);
                acc[8]  += wB * bf2f_lo(vbB.x); acc[9]  += wB * bf2f_hi(vbB.x);
                acc[10] += wB * bf2f_lo(vbB.y); acc[11] += wB * bf2f_hi(vbB.y);
                acc[12] += wB * bf2f_lo(vbB.z); acc[13] += wB * bf2f_hi(vbB.z);
                acc[14] += wB * bf2f_lo(vbB.w); acc[15] += wB * bf2f_hi(vbB.w);
            }
        }
        // reduce-scatter over edge-slot bits: 16 -> 8 -> 4 -> 2 dims
        float r8[8];
        #pragma unroll
        for (int d = 0; d < 8; d++) {
            float keep = b0 ? acc[d + 8] : acc[d];
            float give = b0 ? acc[d] : acc[d + 8];
            r8[d] = keep + __shfl_xor(give, 8, 64);
        }
        float r4[4];
        #pragma unroll
        for (int d = 0; d < 4; d++) {
            float keep = b1 ? r8[d + 4] : r8[d];
            float give = b1 ? r8[d] : r8[d + 4];
            r4[d] = keep + __shfl_xor(give, 16, 64);
        }
        float r2[2];
        #pragma unroll
        for (int d = 0; d < 2; d++) {
            float keep = b2 ? r4[d + 2] : r4[d];
            float give = b2 ? r4[d] : r4[d + 2];
            r2[d] = keep + __shfl_xor(give, 32, 64);
        }
        unsigned o = (unsigned)f2bf(r2[0]) | ((unsigned)f2bf(r2[1]) << 16);
        *(unsigned*)&lds[wave * 4 + i][h * 16 + dbase] = o;
    }
    __syncthreads();

    const int m = lane & 15, quad = lane >> 4;
    const int colbase = wave * 32;
    bf16x8 a[4];
    #pragma unroll
    for (int kc = 0; kc < 4; kc++)
        a[kc] = *(const bf16x8*)&lds[m][kc * 32 + quad * 8];

    bf16x8 bfr[2][4];
    #pragma unroll
    for (int ctl = 0; ctl < 2; ctl++) {
        const unsigned short* wrow = Wob + (size_t)(colbase + ctl * 16 + m) * FEAT + quad * 8;
        #pragma unroll
        for (int kc = 0; kc < 4; kc++)
            bfr[ctl][kc] = *(const bf16x8*)(wrow + kc * 32);
    }
    float bias[2];
    #pragma unroll
    for (int ctl = 0; ctl < 2; ctl++) bias[ctl] = bo[colbase + ctl * 16 + m];

    f32x4 acc2[2];
    #pragma unroll
    for (int ctl = 0; ctl < 2; ctl++) acc2[ctl] = (f32x4){0.f, 0.f, 0.f, 0.f};
    #pragma unroll
    for (int kc = 0; kc < 4; kc++)
        #pragma unroll
        for (int ctl = 0; ctl < 2; ctl++)
            acc2[ctl] = __builtin_amdgcn_mfma_f32_16x16x32_bf16(
                a[kc], bfr[ctl][kc], acc2[ctl], 0, 0, 0);

    const int row0 = blockIdx.x * 16;
    #pragma unroll
    for (int ctl = 0; ctl < 2; ctl++)
        #pragma unroll
        for (int reg = 0; reg < 4; reg++) {
            int row = row0 + quad * 4 + reg;
            if (row < N)
                out[(size_t)row * FEAT + colbase + ctl * 16 + m] = acc2[ctl][reg] + bias[ctl];
        }
}

extern "C" void kernel_launch(void* const* d_in, const int* in_sizes, int n_in,
                              void* d_out, int out_size, void* d_ws, size_t ws_size,
                              hipStream_t stream) {
    const float* X  = (const float*)d_in[0];
    const int*   ei = (const int*)d_in[1];
    const float* Wq = (const float*)d_in[2];
    const float* bq = (const float*)d_in[3];
    const float* Wk = (const float*)d_in[4];
    const float* bk = (const float*)d_in[5];
    const float* Wv = (const float*)d_in[6];
    const float* bv = (const float*)d_in[7];
    const float* Wo = (const float*)d_in[8];
    const float* bo = (const float*)d_in[9];
    float* out = (float*)d_out;

    const int N = in_sizes[0] / FEAT;        // 50000
    const int E = in_sizes[1] / 2;           // 600000
    const int* srcs = ei;
    const int* dsts = ei + E;
    const size_t NF2 = (size_t)NPAD * FEAT * 2;

    char* w = (char*)d_ws;
    unsigned short* Xb = (unsigned short*)w;  w += NF2;
    unsigned short* Qb = (unsigned short*)w;  w += NF2;
    unsigned short* Kb = (unsigned short*)w;  w += NF2;
    unsigned short* Vb = (unsigned short*)w;  w += NF2;
    unsigned short* Wb = (unsigned short*)w;  w += (size_t)4 * 16384 * 2;
    unsigned short* wrawb = (unsigned short*)w; w += (size_t)E * NHEAD * 2;  // bf16
    float* segsum      = (float*)w;           w += (size_t)N * NHEAD * 4;  // zeroed by scan12
    int* counts        = (int*)w;             w += (size_t)N * 4;          // zeroed (memset)
    int* done          = (int*)w;             w += 16;                      // zeroed (memset)
    int* offsets       = (int*)w;             w += (size_t)N * 4;
    int* blocksums     = (int*)w;             w += 256 * 4;
    int* blockoffs     = (int*)w;             w += 256 * 4;
    int* rec           = (int*)w;             w += (size_t)E * 4;
    int* rank          = (int*)w;             w += (size_t)E * 4;

    // zero counts + done (contiguous)
    hipMemsetAsync(counts, 0, (size_t)N * 4 + 16, stream);

    int e_blocks = (E + 255) / 256;          // 2344
    int x8 = N * FEAT / 8;
    int convx_blocks = (x8 + 255) / 256;     // 3125
    int convw_blocks = 32;
    prep_kernel<<<e_blocks + convx_blocks + convw_blocks, 256, 0, stream>>>(
        dsts, counts, rank, X, Xb, x8, Wq, Wk, Wv, Wo, Wb,
        E, e_blocks, convx_blocks);

    int NB = (N + 255) / 256;   // 196
    scan12_kernel<<<NB, 256, 0, stream>>>(
        counts, offsets, blocksums, blockoffs, done, (float4*)segsum, N, NB, N);

    int numTiles = NPAD / 16;   // 3128
    int qkvBlocks = 782;
    fillqkv_kernel<<<qkvBlocks + e_blocks, 256, 0, stream>>>(
        Xb, Wb, bq, bk, bv, Qb, Kb, Vb, N, numTiles, qkvBlocks,
        srcs, dsts, rank, offsets, blockoffs, rec, E);

    int node_blocks = (N + 3) / 4;
    sumexp_kernel<<<node_blocks, 256, 0, stream>>>(
        offsets, blockoffs, counts, rec, Qb, Kb, wrawb, segsum, N);

    scalev_kernel<<<(N * 16 + 255) / 256, 256, 0, stream>>>(segsum, Vb, N * 16);

    gatherout_kernel<<<(N + 15) / 16, 256, 0, stream>>>(
        offsets, blockoffs, counts, rec, wrawb, Vb, Wb + 3 * 16384, bo, out, N);
}